// Round 13
// baseline (198.630 us; speedup 1.0000x reference)
//
#include <hip/hip_runtime.h>

// Cross-attention: B=8, P=512, S=2048, D_MODEL=1024, H=16, HD=64
#define DM 1024
#define B_ 8
#define P_ 512
#define S_ 2048

typedef __bf16 bf16;
typedef __bf16 bf16x4 __attribute__((ext_vector_type(4)));
typedef __bf16 bf16x8 __attribute__((ext_vector_type(8)));
typedef float f32x4 __attribute__((ext_vector_type(4)));
typedef float f32x16 __attribute__((ext_vector_type(16)));

__device__ __forceinline__ void gload_lds16(const void* g, void* l) {
  __builtin_amdgcn_global_load_lds(
      (const __attribute__((address_space(1))) unsigned int*)g,
      (__attribute__((address_space(3))) unsigned int*)l, 16, 0, 0);
}

__device__ __forceinline__ f32x4 mfma16(bf16x8 a, bf16x8 b, f32x4 c) {
  return __builtin_amdgcn_mfma_f32_16x16x32_bf16(a, b, c, 0, 0, 0);
}
__device__ __forceinline__ f32x16 mfma32(bf16x8 a, bf16x8 b, f32x16 c) {
  return __builtin_amdgcn_mfma_f32_32x32x16_bf16(a, b, c, 0, 0, 0);
}

__device__ __forceinline__ unsigned cvt_pk_bf16(float lo, float hi) {
  unsigned r;
  asm("v_cvt_pk_bf16_f32 %0, %1, %2" : "=v"(r) : "v"(lo), "v"(hi));
  return r;
}
// v_permlane32_swap_b32: new_a = {a.lo, b.lo}, new_b = {a.hi, b.hi}
__device__ __forceinline__ void plswap(unsigned& a, unsigned& b) {
  asm volatile("s_nop 1\n\tv_permlane32_swap_b32 %0, %1" : "+v"(a), "+v"(b));
}
__device__ __forceinline__ void bar() {
  asm volatile("" ::: "memory");
  __builtin_amdgcn_s_barrier();
  asm volatile("" ::: "memory");
}

union U8 { unsigned u[4]; bf16x8 v; };

// scale folded into Q projection: 1/sqrt(64) * log2(e)
#define QSCALE 0.18033688011112042f

// ---------------- fused f32 -> bf16 conversion (all 6 tensors, 1 launch) ----
__global__ void cvt_all(const float* __restrict__ ts, const float* __restrict__ llm,
                        const float* __restrict__ qw, const float* __restrict__ kw,
                        const float* __restrict__ vw, const float* __restrict__ ow,
                        bf16* __restrict__ ts_o, bf16* __restrict__ llm_o,
                        bf16* __restrict__ qw_o, bf16* __restrict__ kw_o,
                        bf16* __restrict__ vw_o, bf16* __restrict__ ow_o) {
  const int total = 24 << 18;
  int i = blockIdx.x * blockDim.x + threadIdx.x;
  const int stride = gridDim.x * blockDim.x;
  for (; i < total; i += stride) {
    int r = i >> 18;
    const float* in;
    bf16* out;
    int off;
    if (r < 4) { in = ts; out = ts_o; off = i; }
    else if (r < 20) { in = llm; out = llm_o; off = i - (4 << 18); }
    else if (r == 20) { in = qw; out = qw_o; off = i - (20 << 18); }
    else if (r == 21) { in = kw; out = kw_o; off = i - (21 << 18); }
    else if (r == 22) { in = vw; out = vw_o; off = i - (22 << 18); }
    else { in = ow; out = ow_o; off = i - (23 << 18); }
    float4 v = reinterpret_cast<const float4*>(in)[off];
    bf16x4 o;
    o[0] = (bf16)v.x; o[1] = (bf16)v.y; o[2] = (bf16)v.z; o[3] = (bf16)v.w;
    reinterpret_cast<bf16x4*>(out)[off] = o;
  }
}

enum { MODE_F32 = 0, MODE_Q = 1 };

// ---------------- 128x128 BT GEMM (m97 structure) for Q and O projections ----
template <int MODE>
__global__ __launch_bounds__(256) void gemm_bt(
    const bf16* __restrict__ A, const bf16* __restrict__ Bw,
    const float* __restrict__ bias, void* __restrict__ out) {
  __shared__ char As[16384];  // [128 rows][64 k * 2B]
  __shared__ char Bs[16384];
  const int tid = threadIdx.x;
  const int w = tid >> 6, lane = tid & 63;
  const int g = lane >> 4, l15 = lane & 15;
  const int tn = blockIdx.x, tm = blockIdx.y;
  const int wm = w >> 1, wn = w & 1;

  f32x4 acc[4][4] = {};

  const char* Abase = (const char*)A + (size_t)(tm * 128) * (DM * 2);
  const char* Bbase = (const char*)Bw + (size_t)(tn * 128) * (DM * 2);

  for (int kt = 0; kt < DM / 64; ++kt) {
#pragma unroll
    for (int i = 0; i < 4; ++i) {
      int f = (w * 4 + i) * 1024 + lane * 16;
      int row = f >> 7;          // 128B per row (64 bf16)
      int kb = f & 127;
      int src = kb ^ ((row & 7) << 4);
      gload_lds16(Abase + (size_t)row * (DM * 2) + kt * 128 + src, As + (w * 4 + i) * 1024);
      gload_lds16(Bbase + (size_t)row * (DM * 2) + kt * 128 + src, Bs + (w * 4 + i) * 1024);
    }
    __syncthreads();
#pragma unroll
    for (int kk = 0; kk < 2; ++kk) {
      bf16x8 af[4], bfr[4];
#pragma unroll
      for (int mi = 0; mi < 4; ++mi) {
        int row = wm * 64 + mi * 16 + l15;
        int off = row * 128 + ((kk * 64 + g * 16) ^ ((row & 7) << 4));
        af[mi] = *reinterpret_cast<const bf16x8*>(As + off);
      }
#pragma unroll
      for (int ni = 0; ni < 4; ++ni) {
        int row = wn * 64 + ni * 16 + l15;
        int off = row * 128 + ((kk * 64 + g * 16) ^ ((row & 7) << 4));
        bfr[ni] = *reinterpret_cast<const bf16x8*>(Bs + off);
      }
#pragma unroll
      for (int mi = 0; mi < 4; ++mi)
#pragma unroll
        for (int ni = 0; ni < 4; ++ni)
          acc[mi][ni] = mfma16(af[mi], bfr[ni], acc[mi][ni]);
    }
    __syncthreads();
  }

#pragma unroll
  for (int mi = 0; mi < 4; ++mi) {
#pragma unroll
    for (int ni = 0; ni < 4; ++ni) {
      const int n = tn * 128 + wn * 64 + ni * 16 + l15;
      const float bn = bias[n];
      const int mb = tm * 128 + wm * 64 + mi * 16 + g * 4;
#pragma unroll
      for (int r = 0; r < 4; ++r) {
        const int m = mb + r;
        const float v = acc[mi][ni][r] + bn;
        if constexpr (MODE == MODE_F32) {
          ((float*)out)[(size_t)m * 1024 + n] = v;
        } else {  // MODE_Q: fold softmax scale*log2e into Q
          const int b = m >> 9, p = m & 511, h = n >> 6, d = n & 63;
          ((bf16*)out)[((size_t)((b * 16 + h) * 512 + p)) * 64 + d] = (bf16)(v * QSCALE);
        }
      }
    }
  }
}

// ------- 256x256 4-phase pipelined BT GEMM, K+V projections fused (N=2048) ---
// (r10 version — the read-hoist variant measured neutral, reverted)
__global__ __launch_bounds__(512, 2) void gemm256kv(
    const bf16* __restrict__ A, const bf16* __restrict__ Bw,
    const float* __restrict__ kb, const float* __restrict__ vb,
    bf16* __restrict__ Kout, bf16* __restrict__ VTout) {
  __shared__ char lds[131072];  // A: [0,64K), B: [64K,128K)
  const int tid = threadIdx.x;
  const int w = tid >> 6, lane = tid & 63;
  const int g = lane >> 4, l15 = lane & 15;
  const int wm = w >> 2, wn = w & 3;

  const int id = blockIdx.x;
  const int nid = (id & 7) * 64 + (id >> 3);
  const int tn = nid & 7, tm = nid >> 3;

  const int f0 = tid * 16, f1 = f0 + 8192;
  const int r0 = f0 >> 7, r1 = f1 >> 7;
  const size_t so0 = (size_t)r0 * 2048 + ((f0 & 127) ^ ((r0 & 7) << 4));
  const size_t so1 = (size_t)r1 * 2048 + ((f1 & 127) ^ ((r1 & 7) << 4));

  const char* Ab = (const char*)A + (size_t)(tm * 256) * 2048;
  const char* Bb = (const char*)Bw + (size_t)(tn * 256) * 2048;

#define STG(OP, HALF, KT)                                                      \
  {                                                                            \
    const char* base = ((OP) ? Bb : Ab) + (size_t)((HALF) * 128) * 2048 +      \
                       (size_t)(KT) * 128;                                     \
    char* dst = lds + (OP) * 65536 + ((((KT) & 1) * 2 + (HALF)) * 16384);      \
    gload_lds16(base + so0, dst + f0);                                         \
    gload_lds16(base + so1, dst + f1);                                         \
  }

  f32x4 acc[8][4] = {};
  bf16x8 a[4][2], b0[2][2], b1[2][2];

#define RD_A(MH)                                                               \
  _Pragma("unroll") for (int mi = 0; mi < 4; ++mi) _Pragma("unroll")           \
      for (int kk = 0; kk < 2; ++kk) {                                         \
    int lr = (MH) * 64 + mi * 16 + l15;                                        \
    int off = (((unsigned)(kt & 1) * 2 + wm) * 16384) + lr * 128 +             \
              ((kk * 64 + g * 16) ^ ((lr & 7) << 4));                          \
    a[mi][kk] = *reinterpret_cast<const bf16x8*>(lds + off);                   \
  }
#define RD_B(NH, DST)                                                          \
  _Pragma("unroll") for (int ni = 0; ni < 2; ++ni) _Pragma("unroll")           \
      for (int kk = 0; kk < 2; ++kk) {                                         \
    int lr = (wn & 1) * 64 + ((NH) * 2 + ni) * 16 + l15;                       \
    int off = 65536 + (((unsigned)(kt & 1) * 2 + (wn >> 1)) * 16384) +         \
              lr * 128 + ((kk * 64 + g * 16) ^ ((lr & 7) << 4));               \
    DST[ni][kk] = *reinterpret_cast<const bf16x8*>(lds + off);                 \
  }
#define MM(MH, NH, B)                                                          \
  __builtin_amdgcn_s_setprio(1);                                              \
  _Pragma("unroll") for (int mi = 0; mi < 4; ++mi) _Pragma("unroll")           \
      for (int ni = 0; ni < 2; ++ni) _Pragma("unroll")                         \
      for (int kk = 0; kk < 2; ++kk)                                           \
          acc[(MH)*4 + mi][(NH)*2 + ni] =                                      \
              mfma16(a[mi][kk], B[ni][kk], acc[(MH)*4 + mi][(NH)*2 + ni]);     \
  __builtin_amdgcn_s_setprio(0);

  STG(0, 0, 0); STG(1, 0, 0); STG(0, 1, 0); STG(1, 1, 0);
  STG(1, 1, 1); STG(0, 0, 1); STG(1, 0, 1);
  asm volatile("s_waitcnt vmcnt(6)" ::: "memory");
  bar();

  for (int kt = 0; kt < 16; ++kt) {
    RD_A(0); RD_B(0, b0);
    if (kt + 1 < 16) STG(0, 1, kt + 1);
    bar();
    MM(0, 0, b0);
    bar();
    RD_B(1, b1);
    bar();
    MM(0, 1, b1);
    bar();
    RD_A(1);
    if (kt + 2 < 16) STG(1, 1, kt + 2);
    bar();
    MM(1, 0, b0);
    bar();
    if (kt + 2 < 16) { STG(0, 0, kt + 2); STG(1, 0, kt + 2); }
    if (kt < 14) {
      asm volatile("s_waitcnt vmcnt(6)" ::: "memory");
    } else {
      asm volatile("s_waitcnt vmcnt(0)" ::: "memory");
    }
    bar();
    MM(1, 1, b1);
    bar();
  }

#pragma unroll
  for (int am = 0; am < 8; ++am) {
#pragma unroll
    for (int an = 0; an < 4; ++an) {
      const int n = tn * 256 + wn * 64 + an * 16 + l15;
      const int mb = tm * 256 + wm * 128 + am * 16 + g * 4;
      const int b = mb >> 11, s = mb & 2047;
      if (n >= 1024) {  // VT output: [B][H][64][S], rows r = consecutive s
        const int h = (n - 1024) >> 6, d = (n - 1024) & 63;
        const float bn = vb[n - 1024];
        bf16x4 pk;
#pragma unroll
        for (int r = 0; r < 4; ++r) pk[r] = (bf16)(acc[am][an][r] + bn);
        *reinterpret_cast<bf16x4*>(VTout + ((size_t)((b * 16 + h) * 64 + d)) * 2048 + s) = pk;
      } else {  // K output: [B][H][S][64]
        const int h = n >> 6, d = n & 63;
        const float bn = kb[n];
#pragma unroll
        for (int r = 0; r < 4; ++r)
          Kout[((size_t)((b * 16 + h) * 2048 + s + r)) * 64 + d] =
              (bf16)(acc[am][an][r] + bn);
      }
    }
  }
#undef STG
#undef RD_A
#undef RD_B
#undef MM
}

// ---- Flash attention: 64 q/wave (2 sets), 32-kv-granular, split-S=2 --------
// r10's proven sync skeleton. Each wave owns TWO 32-q column sets that share
// every K/V fragment read -> per-CU ds_read count halves vs r10. 32-kv tile
// granularity keeps transient regs small (kf[4]+vf[4]+sa+sb+pf*4 ~ 80) so
// total VGPR ~200 < 256 cap (r11's spill confound removed).
// Grid 512 = 128 bh x 2 qh x 2 sh; fixed-max partials additive (r4-proven).
__global__ __launch_bounds__(256, 2) void attn_kernel(
    const bf16* __restrict__ Q, const bf16* __restrict__ K,
    const bf16* __restrict__ VT, float* __restrict__ Opart,
    float* __restrict__ lpart) {
  __shared__ char lds[65536];
  const int tid = threadIdx.x;
  const int w = tid >> 6, lane = tid & 63;
  const int l31 = lane & 31, hi = lane >> 5;

  const int n = blockIdx.x;
  const int wid = (n & 7) * 64 + (n >> 3);  // bijective; 4 blocks/bh same XCD
  const int bh = wid >> 2;
  const int qh = (wid >> 1) & 1;
  const int sh = wid & 1;
  const int q0 = qh * 256;
  const int sbase = sh * 1024;

  const char* Kb = (const char*)(K + (size_t)bh * 2048 * 64);
  const char* Vb = (const char*)(VT + (size_t)bh * 64 * 2048);

  // two q-sets per wave: A = q0 + w*64 + l31, B = A + 32
  const char* QrowA = (const char*)(Q + ((size_t)bh * 512 + q0 + w * 64 + l31) * 64);
  bf16x8 qfA[4], qfB[4];
#pragma unroll
  for (int kk = 0; kk < 4; ++kk) {
    qfA[kk] = *reinterpret_cast<const bf16x8*>(QrowA + kk * 32 + hi * 16);
    qfB[kk] = *reinterpret_cast<const bf16x8*>(QrowA + 4096 + kk * 32 + hi * 16);
  }

  float lrunA = 0.f, lrunB = 0.f;
  f32x16 oaccA[2] = {}, oaccB[2] = {};

#define STAGE(S0, BUF)                                                        \
  {                                                                           \
    _Pragma("unroll") for (int i = 0; i < 4; ++i) {                           \
      int f = i * 4096 + (w * 64 + lane) * 16;                                \
      int krow = f >> 7, kbyte = f & 127;                                     \
      gload_lds16(Kb + (size_t)((S0) + krow) * 128 +                          \
                      (kbyte ^ ((krow & 7) << 4)),                            \
                  (BUF) + i * 4096 + w * 1024);                               \
      int vrow = f >> 8, vbyte = f & 255;                                     \
      gload_lds16(Vb + (size_t)vrow * 4096 + (size_t)(S0) * 2 +               \
                      (vbyte ^ ((vrow & 7) << 4)),                            \
                  (BUF) + 16384 + i * 4096 + w * 1024);                       \
    }                                                                         \
  }

  // softmax for one 32-s strip held in f32x16 SA -> 2 PV A-frags
#define SOFTMAX32(SA, PF, LRUN)                                               \
  _Pragma("unroll") for (int h2 = 0; h2 < 2; ++h2) {                          \
    float p[8];                                                               \
    _Pragma("unroll") for (int j = 0; j < 8; ++j) {                           \
      p[j] = __builtin_amdgcn_exp2f(SA[8 * h2 + j]);                          \
      LRUN += p[j];                                                           \
    }                                                                         \
    unsigned a0 = cvt_pk_bf16(p[0], p[1]);                                    \
    unsigned a1 = cvt_pk_bf16(p[2], p[3]);                                    \
    unsigned a2 = cvt_pk_bf16(p[4], p[5]);                                    \
    unsigned a3 = cvt_pk_bf16(p[6], p[7]);                                    \
    plswap(a0, a2);                                                           \
    plswap(a1, a3);                                                           \
    U8 u;                                                                     \
    u.u[0] = a0; u.u[1] = a1; u.u[2] = a2; u.u[3] = a3;                       \
    PF[h2] = u.v;                                                             \
  }

  // one 32-kv tile T in [0,4): shared kf/vf reads feed BOTH q-sets
#define SUBTILE32(T, CUR)                                                     \
  {                                                                           \
    bf16x8 kf[4];                                                             \
    _Pragma("unroll") for (int kk = 0; kk < 4; ++kk) {                        \
      int row = (T) * 32 + l31;                                               \
      int off = row * 128 + ((kk * 32 + hi * 16) ^ ((row & 7) << 4));         \
      kf[kk] = *reinterpret_cast<const bf16x8*>((CUR) + off);                 \
    }                                                                         \
    f32x16 sa = {}, sb = {};                                                  \
    __builtin_amdgcn_s_setprio(1);                                            \
    _Pragma("unroll") for (int kk = 0; kk < 4; ++kk)                          \
        sa = mfma32(kf[kk], qfA[kk], sa);                                     \
    _Pragma("unroll") for (int kk = 0; kk < 4; ++kk)                          \
        sb = mfma32(kf[kk], qfB[kk], sb);                                     \
    __builtin_amdgcn_s_setprio(0);                                            \
    bf16x8 vf[4];                                                             \
    _Pragma("unroll") for (int dt = 0; dt < 2; ++dt)                          \
        _Pragma("unroll") for (int ks = 0; ks < 2; ++ks) {                    \
      int row = dt * 32 + l31;                                                \
      int col = (T) * 64 + ks * 32 + hi * 16;                                 \
      int off = 16384 + row * 256 + (col ^ ((row & 7) << 4));                 \
      vf[dt * 2 + ks] = *reinterpret_cast<const bf16x8*>((CUR) + off);        \
    }                                                                         \
    bf16x8 pfA[2], pfB[2];                                                    \
    SOFTMAX32(sa, pfA, lrunA);                                                \
    SOFTMAX32(sb, pfB, lrunB);                                                \
    __builtin_amdgcn_s_setprio(1);                                            \
    _Pragma("unroll") for (int dt = 0; dt < 2; ++dt)                          \
        _Pragma("unroll") for (int ks = 0; ks < 2; ++ks) {                    \
      oaccA[dt] = mfma32(vf[dt * 2 + ks], pfA[ks], oaccA[dt]);                \
      oaccB[dt] = mfma32(vf[dt * 2 + ks], pfB[ks], oaccB[dt]);                \
    }                                                                         \
    __builtin_amdgcn_s_setprio(0);                                            \
  }

  STAGE(sbase, lds);

  for (int c = 0; c < 8; ++c) {
    char* cur = lds + (c & 1) * 32768;
    if (c + 1 < 8) {
      STAGE(sbase + (c + 1) * 128, lds + ((c + 1) & 1) * 32768);
      asm volatile("s_waitcnt vmcnt(8)" ::: "memory");  // current tile landed
    } else {
      asm volatile("s_waitcnt vmcnt(0)" ::: "memory");
    }
    bar();

    SUBTILE32(0, cur);
    SUBTILE32(1, cur);
    SUBTILE32(2, cur);
    SUBTILE32(3, cur);

    bar();  // all waves done reading cur before restage
  }

  // partial epilogue: Opart[sh][bh*512+prow][d], lpart[sh][...]
  lrunA += __shfl_xor(lrunA, 32);
  lrunB += __shfl_xor(lrunB, 32);
  const size_t rowgA = (size_t)bh * 512 + q0 + w * 64 + l31;
  const size_t rowgB = rowgA + 32;
  float* OdA = Opart + ((size_t)sh * 65536 + rowgA) * 64;
  float* OdB = Opart + ((size_t)sh * 65536 + rowgB) * 64;
  if (hi == 0) {
    lpart[(size_t)sh * 65536 + rowgA] = lrunA;
    lpart[(size_t)sh * 65536 + rowgB] = lrunB;
  }
#pragma unroll
  for (int dt = 0; dt < 2; ++dt)
#pragma unroll
    for (int g4 = 0; g4 < 4; ++g4) {
      f32x4 stA, stB;
#pragma unroll
      for (int r = 0; r < 4; ++r) {
        stA[r] = oaccA[dt][g4 * 4 + r];
        stB[r] = oaccB[dt][g4 * 4 + r];
      }
      *reinterpret_cast<f32x4*>(OdA + dt * 32 + g4 * 8 + hi * 4) = stA;
      *reinterpret_cast<f32x4*>(OdB + dt * 32 + g4 * 8 + hi * 4) = stB;
    }
#undef STAGE
#undef SOFTMAX32
#undef SUBTILE32
}

// ---------------- combine split-S partials -> ctx bf16 ----------------
__global__ __launch_bounds__(256) void combine_kernel(
    const float* __restrict__ Opart, const float* __restrict__ lpart,
    bf16* __restrict__ ctx) {
  int idx = blockIdx.x * blockDim.x + threadIdx.x;  // 65536 rows x 8 d-chunks
  int row = idx >> 3, dc = (idx & 7) * 8;
  const float* o0 = Opart + (size_t)row * 64 + dc;
  const float* o1 = o0 + (size_t)65536 * 64;
  float inv = 1.0f / (lpart[row] + lpart[65536 + row]);
  float4 a0 = *(const float4*)o0;
  float4 a1 = *(const float4*)(o0 + 4);
  float4 c0 = *(const float4*)o1;
  float4 c1 = *(const float4*)(o1 + 4);
  int bh = row >> 9, p = row & 511;
  int b = bh >> 4, h = bh & 15;
  bf16* dst = ctx + ((size_t)(b * 512 + p)) * 1024 + h * 64 + dc;
  bf16x8 o;
  o[0] = (bf16)((a0.x + c0.x) * inv);
  o[1] = (bf16)((a0.y + c0.y) * inv);
  o[2] = (bf16)((a0.z + c0.z) * inv);
  o[3] = (bf16)((a0.w + c0.w) * inv);
  o[4] = (bf16)((a1.x + c1.x) * inv);
  o[5] = (bf16)((a1.y + c1.y) * inv);
  o[6] = (bf16)((a1.z + c1.z) * inv);
  o[7] = (bf16)((a1.w + c1.w) * inv);
  *reinterpret_cast<bf16x8*>(dst) = o;
}

// ---------------- launch ----------------
extern "C" void kernel_launch(void* const* d_in, const int* in_sizes, int n_in,
                              void* d_out, int out_size, void* d_ws, size_t ws_size,
                              hipStream_t stream) {
  const float* ts = (const float*)d_in[0];
  const float* llm = (const float*)d_in[1];
  const float* qw = (const float*)d_in[2];
  const float* qb = (const float*)d_in[3];
  const float* kw = (const float*)d_in[4];
  const float* kb = (const float*)d_in[5];
  const float* vw = (const float*)d_in[6];
  const float* vb = (const float*)d_in[7];
  const float* ow = (const float*)d_in[8];
  const float* ob = (const float*)d_in[9];

  char* ws = (char*)d_ws;
  bf16* ts_bf = (bf16*)(ws + (0ull << 20));    // 8 MB   } dead after gemms;
  bf16* llm_bf = (bf16*)(ws + (8ull << 20));   // 32 MB  } reused as Opart/lpart
  bf16* qw_bf = (bf16*)(ws + (40ull << 20));   // 2 MB
  bf16* kw_bf = (bf16*)(ws + (42ull << 20));   // 2 MB  } adjacent: [kw;vw]
  bf16* vw_bf = (bf16*)(ws + (44ull << 20));   // 2 MB  } = 2048x1024 concat
  bf16* ow_bf = (bf16*)(ws + (46ull << 20));   // 2 MB
  bf16* Qb = (bf16*)(ws + (48ull << 20));      // 8 MB  [B,H,P,64] (pre-scaled)
  bf16* Kb = (bf16*)(ws + (56ull << 20));      // 32 MB [B,H,S,64]
  bf16* VTb = (bf16*)(ws + (88ull << 20));     // 32 MB [B,H,64,S]
  bf16* ctx = (bf16*)(ws + (120ull << 20));    // 8 MB  [B,P,1024]
  float* Opart = (float*)(ws + (0ull << 20));  // 32 MB [2][65536][64] f32
  float* lpart = (float*)(ws + (32ull << 20)); // 0.5 MB [2][65536] f32

  cvt_all<<<2048, 256, 0, stream>>>(ts, llm, qw, kw, vw, ow,
                                    ts_bf, llm_bf, qw_bf, kw_bf, vw_bf, ow_bf);

  gemm_bt<MODE_Q><<<dim3(8, 32), 256, 0, stream>>>(ts_bf, qw_bf, qb, Qb);
  gemm256kv<<<512, 512, 0, stream>>>(llm_bf, kw_bf, kb, vb, Kb, VTb);
  attn_kernel<<<512, 256, 0, stream>>>(Qb, Kb, VTb, Opart, lpart);
  combine_kernel<<<2048, 256, 0, stream>>>(Opart, lpart, ctx);
  gemm_bt<MODE_F32><<<dim3(8, 32), 256, 0, stream>>>(ctx, ow_bf, ob, (void*)d_out);
}

// Round 14
// 194.601 us; speedup vs baseline: 1.0207x; 1.0207x over previous
//
#include <hip/hip_runtime.h>

// Cross-attention: B=8, P=512, S=2048, D_MODEL=1024, H=16, HD=64
#define DM 1024
#define B_ 8
#define P_ 512
#define S_ 2048

typedef __bf16 bf16;
typedef __bf16 bf16x4 __attribute__((ext_vector_type(4)));
typedef __bf16 bf16x8 __attribute__((ext_vector_type(8)));
typedef float f32x4 __attribute__((ext_vector_type(4)));
typedef float f32x16 __attribute__((ext_vector_type(16)));

__device__ __forceinline__ void gload_lds16(const void* g, void* l) {
  __builtin_amdgcn_global_load_lds(
      (const __attribute__((address_space(1))) unsigned int*)g,
      (__attribute__((address_space(3))) unsigned int*)l, 16, 0, 0);
}

__device__ __forceinline__ f32x4 mfma16(bf16x8 a, bf16x8 b, f32x4 c) {
  return __builtin_amdgcn_mfma_f32_16x16x32_bf16(a, b, c, 0, 0, 0);
}
__device__ __forceinline__ f32x16 mfma32(bf16x8 a, bf16x8 b, f32x16 c) {
  return __builtin_amdgcn_mfma_f32_32x32x16_bf16(a, b, c, 0, 0, 0);
}

__device__ __forceinline__ unsigned cvt_pk_bf16(float lo, float hi) {
  unsigned r;
  asm("v_cvt_pk_bf16_f32 %0, %1, %2" : "=v"(r) : "v"(lo), "v"(hi));
  return r;
}
// v_permlane32_swap_b32: new_a = {a.lo, b.lo}, new_b = {a.hi, b.hi}
__device__ __forceinline__ void plswap(unsigned& a, unsigned& b) {
  asm volatile("s_nop 1\n\tv_permlane32_swap_b32 %0, %1" : "+v"(a), "+v"(b));
}
__device__ __forceinline__ void bar() {
  asm volatile("" ::: "memory");
  __builtin_amdgcn_s_barrier();
  asm volatile("" ::: "memory");
}

union U8 { unsigned u[4]; bf16x8 v; };

// scale folded into Q projection: 1/sqrt(64) * log2(e)
#define QSCALE 0.18033688011112042f

// ---------------- fused f32 -> bf16 conversion (all 6 tensors, 1 launch) ----
__global__ void cvt_all(const float* __restrict__ ts, const float* __restrict__ llm,
                        const float* __restrict__ qw, const float* __restrict__ kw,
                        const float* __restrict__ vw, const float* __restrict__ ow,
                        bf16* __restrict__ ts_o, bf16* __restrict__ llm_o,
                        bf16* __restrict__ qw_o, bf16* __restrict__ kw_o,
                        bf16* __restrict__ vw_o, bf16* __restrict__ ow_o) {
  const int total = 24 << 18;
  int i = blockIdx.x * blockDim.x + threadIdx.x;
  const int stride = gridDim.x * blockDim.x;
  for (; i < total; i += stride) {
    int r = i >> 18;
    const float* in;
    bf16* out;
    int off;
    if (r < 4) { in = ts; out = ts_o; off = i; }
    else if (r < 20) { in = llm; out = llm_o; off = i - (4 << 18); }
    else if (r == 20) { in = qw; out = qw_o; off = i - (20 << 18); }
    else if (r == 21) { in = kw; out = kw_o; off = i - (21 << 18); }
    else if (r == 22) { in = vw; out = vw_o; off = i - (22 << 18); }
    else { in = ow; out = ow_o; off = i - (23 << 18); }
    float4 v = reinterpret_cast<const float4*>(in)[off];
    bf16x4 o;
    o[0] = (bf16)v.x; o[1] = (bf16)v.y; o[2] = (bf16)v.z; o[3] = (bf16)v.w;
    reinterpret_cast<bf16x4*>(out)[off] = o;
  }
}

enum { MODE_F32 = 0, MODE_Q = 1 };

// ---------------- 128x128 BT GEMM (m97 structure) for Q and O projections ----
template <int MODE>
__global__ __launch_bounds__(256) void gemm_bt(
    const bf16* __restrict__ A, const bf16* __restrict__ Bw,
    const float* __restrict__ bias, void* __restrict__ out) {
  __shared__ char As[16384];  // [128 rows][64 k * 2B]
  __shared__ char Bs[16384];
  const int tid = threadIdx.x;
  const int w = tid >> 6, lane = tid & 63;
  const int g = lane >> 4, l15 = lane & 15;
  const int tn = blockIdx.x, tm = blockIdx.y;
  const int wm = w >> 1, wn = w & 1;

  f32x4 acc[4][4] = {};

  const char* Abase = (const char*)A + (size_t)(tm * 128) * (DM * 2);
  const char* Bbase = (const char*)Bw + (size_t)(tn * 128) * (DM * 2);

  for (int kt = 0; kt < DM / 64; ++kt) {
#pragma unroll
    for (int i = 0; i < 4; ++i) {
      int f = (w * 4 + i) * 1024 + lane * 16;
      int row = f >> 7;          // 128B per row (64 bf16)
      int kb = f & 127;
      int src = kb ^ ((row & 7) << 4);
      gload_lds16(Abase + (size_t)row * (DM * 2) + kt * 128 + src, As + (w * 4 + i) * 1024);
      gload_lds16(Bbase + (size_t)row * (DM * 2) + kt * 128 + src, Bs + (w * 4 + i) * 1024);
    }
    __syncthreads();
#pragma unroll
    for (int kk = 0; kk < 2; ++kk) {
      bf16x8 af[4], bfr[4];
#pragma unroll
      for (int mi = 0; mi < 4; ++mi) {
        int row = wm * 64 + mi * 16 + l15;
        int off = row * 128 + ((kk * 64 + g * 16) ^ ((row & 7) << 4));
        af[mi] = *reinterpret_cast<const bf16x8*>(As + off);
      }
#pragma unroll
      for (int ni = 0; ni < 4; ++ni) {
        int row = wn * 64 + ni * 16 + l15;
        int off = row * 128 + ((kk * 64 + g * 16) ^ ((row & 7) << 4));
        bfr[ni] = *reinterpret_cast<const bf16x8*>(Bs + off);
      }
#pragma unroll
      for (int mi = 0; mi < 4; ++mi)
#pragma unroll
        for (int ni = 0; ni < 4; ++ni)
          acc[mi][ni] = mfma16(af[mi], bfr[ni], acc[mi][ni]);
    }
    __syncthreads();
  }

#pragma unroll
  for (int mi = 0; mi < 4; ++mi) {
#pragma unroll
    for (int ni = 0; ni < 4; ++ni) {
      const int n = tn * 128 + wn * 64 + ni * 16 + l15;
      const float bn = bias[n];
      const int mb = tm * 128 + wm * 64 + mi * 16 + g * 4;
#pragma unroll
      for (int r = 0; r < 4; ++r) {
        const int m = mb + r;
        const float v = acc[mi][ni][r] + bn;
        if constexpr (MODE == MODE_F32) {
          ((float*)out)[(size_t)m * 1024 + n] = v;
        } else {  // MODE_Q: fold softmax scale*log2e into Q
          const int b = m >> 9, p = m & 511, h = n >> 6, d = n & 63;
          ((bf16*)out)[((size_t)((b * 16 + h) * 512 + p)) * 64 + d] = (bf16)(v * QSCALE);
        }
      }
    }
  }
}

// ------- 256x256 4-phase pipelined BT GEMM, K+V projections fused (N=2048) ---
__global__ __launch_bounds__(512, 2) void gemm256kv(
    const bf16* __restrict__ A, const bf16* __restrict__ Bw,
    const float* __restrict__ kb, const float* __restrict__ vb,
    bf16* __restrict__ Kout, bf16* __restrict__ VTout) {
  __shared__ char lds[131072];  // A: [0,64K), B: [64K,128K)
  const int tid = threadIdx.x;
  const int w = tid >> 6, lane = tid & 63;
  const int g = lane >> 4, l15 = lane & 15;
  const int wm = w >> 2, wn = w & 3;

  const int id = blockIdx.x;
  const int nid = (id & 7) * 64 + (id >> 3);
  const int tn = nid & 7, tm = nid >> 3;

  const int f0 = tid * 16, f1 = f0 + 8192;
  const int r0 = f0 >> 7, r1 = f1 >> 7;
  const size_t so0 = (size_t)r0 * 2048 + ((f0 & 127) ^ ((r0 & 7) << 4));
  const size_t so1 = (size_t)r1 * 2048 + ((f1 & 127) ^ ((r1 & 7) << 4));

  const char* Ab = (const char*)A + (size_t)(tm * 256) * 2048;
  const char* Bb = (const char*)Bw + (size_t)(tn * 256) * 2048;

#define STG(OP, HALF, KT)                                                      \
  {                                                                            \
    const char* base = ((OP) ? Bb : Ab) + (size_t)((HALF) * 128) * 2048 +      \
                       (size_t)(KT) * 128;                                     \
    char* dst = lds + (OP) * 65536 + ((((KT) & 1) * 2 + (HALF)) * 16384);      \
    gload_lds16(base + so0, dst + f0);                                         \
    gload_lds16(base + so1, dst + f1);                                         \
  }

  f32x4 acc[8][4] = {};
  bf16x8 a[4][2], b0[2][2], b1[2][2];

#define RD_A(MH)                                                               \
  _Pragma("unroll") for (int mi = 0; mi < 4; ++mi) _Pragma("unroll")           \
      for (int kk = 0; kk < 2; ++kk) {                                         \
    int lr = (MH) * 64 + mi * 16 + l15;                                        \
    int off = (((unsigned)(kt & 1) * 2 + wm) * 16384) + lr * 128 +             \
              ((kk * 64 + g * 16) ^ ((lr & 7) << 4));                          \
    a[mi][kk] = *reinterpret_cast<const bf16x8*>(lds + off);                   \
  }
#define RD_B(NH, DST)                                                          \
  _Pragma("unroll") for (int ni = 0; ni < 2; ++ni) _Pragma("unroll")           \
      for (int kk = 0; kk < 2; ++kk) {                                         \
    int lr = (wn & 1) * 64 + ((NH) * 2 + ni) * 16 + l15;                       \
    int off = 65536 + (((unsigned)(kt & 1) * 2 + (wn >> 1)) * 16384) +         \
              lr * 128 + ((kk * 64 + g * 16) ^ ((lr & 7) << 4));               \
    DST[ni][kk] = *reinterpret_cast<const bf16x8*>(lds + off);                 \
  }
#define MM(MH, NH, B)                                                          \
  __builtin_amdgcn_s_setprio(1);                                              \
  _Pragma("unroll") for (int mi = 0; mi < 4; ++mi) _Pragma("unroll")           \
      for (int ni = 0; ni < 2; ++ni) _Pragma("unroll")                         \
      for (int kk = 0; kk < 2; ++kk)                                           \
          acc[(MH)*4 + mi][(NH)*2 + ni] =                                      \
              mfma16(a[mi][kk], B[ni][kk], acc[(MH)*4 + mi][(NH)*2 + ni]);     \
  __builtin_amdgcn_s_setprio(0);

  STG(0, 0, 0); STG(1, 0, 0); STG(0, 1, 0); STG(1, 1, 0);
  STG(1, 1, 1); STG(0, 0, 1); STG(1, 0, 1);
  asm volatile("s_waitcnt vmcnt(6)" ::: "memory");
  bar();

  for (int kt = 0; kt < 16; ++kt) {
    RD_A(0); RD_B(0, b0);
    if (kt + 1 < 16) STG(0, 1, kt + 1);
    bar();
    MM(0, 0, b0);
    bar();
    RD_B(1, b1);
    bar();
    MM(0, 1, b1);
    bar();
    RD_A(1);
    if (kt + 2 < 16) STG(1, 1, kt + 2);
    bar();
    MM(1, 0, b0);
    bar();
    if (kt + 2 < 16) { STG(0, 0, kt + 2); STG(1, 0, kt + 2); }
    if (kt < 14) {
      asm volatile("s_waitcnt vmcnt(6)" ::: "memory");
    } else {
      asm volatile("s_waitcnt vmcnt(0)" ::: "memory");
    }
    bar();
    MM(1, 1, b1);
    bar();
  }

#pragma unroll
  for (int am = 0; am < 8; ++am) {
#pragma unroll
    for (int an = 0; an < 4; ++an) {
      const int n = tn * 256 + wn * 64 + an * 16 + l15;
      const int mb = tm * 256 + wm * 128 + am * 16 + g * 4;
      const int b = mb >> 11, s = mb & 2047;
      if (n >= 1024) {  // VT output: [B][H][64][S], rows r = consecutive s
        const int h = (n - 1024) >> 6, d = (n - 1024) & 63;
        const float bn = vb[n - 1024];
        bf16x4 pk;
#pragma unroll
        for (int r = 0; r < 4; ++r) pk[r] = (bf16)(acc[am][an][r] + bn);
        *reinterpret_cast<bf16x4*>(VTout + ((size_t)((b * 16 + h) * 64 + d)) * 2048 + s) = pk;
      } else {  // K output: [B][H][S][64]
        const int h = n >> 6, d = n & 63;
        const float bn = kb[n];
#pragma unroll
        for (int r = 0; r < 4; ++r)
          Kout[((size_t)((b * 16 + h) * 2048 + s + r)) * 64 + d] =
              (bf16)(acc[am][an][r] + bn);
      }
    }
  }
#undef STG
#undef RD_A
#undef RD_B
#undef MM
}

// ---------------- Flash attention: chunk=128, proven sync skeleton ----------
// STAGE(c+1) -> counted vmcnt -> bar -> compute (two 64-kv sub-tiles) -> bar.
// LDS: 2 x (16KB K[128][128B] + 16KB V[64][256B]) = 64KB; 2 blocks/CU.
__global__ __launch_bounds__(256) void attn_kernel(
    const bf16* __restrict__ Q, const bf16* __restrict__ K,
    const bf16* __restrict__ VT, bf16* __restrict__ ctx) {
  __shared__ char lds[65536];
  const int tid = threadIdx.x;
  const int w = tid >> 6, lane = tid & 63;
  const int l31 = lane & 31, hi = lane >> 5;

  const int n = blockIdx.x;
  const int xcd = n & 7, mm = n >> 3;
  const int bh = xcd + ((mm >> 2) << 3);
  const int qt = mm & 3;
  const int q0 = qt * 128;

  const char* Kb = (const char*)(K + (size_t)bh * 2048 * 64);
  const char* Vb = (const char*)(VT + (size_t)bh * 64 * 2048);

  const char* Qrow = (const char*)(Q + ((size_t)bh * 512 + q0 + w * 32 + l31) * 64);
  bf16x8 qf[4];
#pragma unroll
  for (int kk = 0; kk < 4; ++kk)
    qf[kk] = *reinterpret_cast<const bf16x8*>(Qrow + kk * 32 + hi * 16);

  float lrun = 0.f;
  f32x16 oacc[2] = {};

#define STAGE(S0, BUF)                                                        \
  {                                                                           \
    _Pragma("unroll") for (int i = 0; i < 4; ++i) {                           \
      int f = i * 4096 + (w * 64 + lane) * 16;                                \
      int krow = f >> 7, kbyte = f & 127;                                     \
      gload_lds16(Kb + (size_t)((S0) + krow) * 128 +                          \
                      (kbyte ^ ((krow & 7) << 4)),                            \
                  (BUF) + i * 4096 + w * 1024);                               \
      int vrow = f >> 8, vbyte = f & 255;                                     \
      gload_lds16(Vb + (size_t)vrow * 4096 + (size_t)(S0) * 2 +               \
                      (vbyte ^ ((vrow & 7) << 4)),                            \
                  (BUF) + 16384 + i * 4096 + w * 1024);                       \
    }                                                                         \
  }

#define SUBTILE(T2, CUR)                                                      \
  {                                                                           \
    f32x16 sa[2] = {};                                                        \
    __builtin_amdgcn_s_setprio(1);                                            \
    _Pragma("unroll") for (int t = 0; t < 2; ++t) {                           \
      _Pragma("unroll") for (int kk = 0; kk < 4; ++kk) {                      \
        int row = (T2) * 64 + t * 32 + l31;                                   \
        int off = row * 128 + ((kk * 32 + hi * 16) ^ ((row & 7) << 4));       \
        bf16x8 kf = *reinterpret_cast<const bf16x8*>((CUR) + off);            \
        sa[t] = mfma32(kf, qf[kk], sa[t]);                                    \
      }                                                                       \
    }                                                                         \
    __builtin_amdgcn_s_setprio(0);                                            \
    bf16x8 vf[8];                                                             \
    _Pragma("unroll") for (int dt = 0; dt < 2; ++dt)                          \
        _Pragma("unroll") for (int ks = 0; ks < 4; ++ks) {                    \
      int row = dt * 32 + l31;                                                \
      int col = (T2) * 128 + ks * 32 + hi * 16;                               \
      int off = 16384 + row * 256 + (col ^ ((row & 7) << 4));                 \
      vf[dt * 4 + ks] = *reinterpret_cast<const bf16x8*>((CUR) + off);        \
    }                                                                         \
    bf16x8 pf[4];                                                             \
    _Pragma("unroll") for (int t = 0; t < 2; ++t)                             \
        _Pragma("unroll") for (int h2 = 0; h2 < 2; ++h2) {                    \
      float p[8];                                                             \
      _Pragma("unroll") for (int j = 0; j < 8; ++j) {                         \
        p[j] = __builtin_amdgcn_exp2f(sa[t][8 * h2 + j]);                     \
        lrun += p[j];                                                         \
      }                                                                       \
      unsigned a0 = cvt_pk_bf16(p[0], p[1]);                                  \
      unsigned a1 = cvt_pk_bf16(p[2], p[3]);                                  \
      unsigned a2 = cvt_pk_bf16(p[4], p[5]);                                  \
      unsigned a3 = cvt_pk_bf16(p[6], p[7]);                                  \
      plswap(a0, a2);                                                         \
      plswap(a1, a3);                                                         \
      U8 u;                                                                   \
      u.u[0] = a0; u.u[1] = a1; u.u[2] = a2; u.u[3] = a3;                     \
      pf[t * 2 + h2] = u.v;                                                   \
    }                                                                         \
    __builtin_amdgcn_s_setprio(1);                                            \
    _Pragma("unroll") for (int dt = 0; dt < 2; ++dt)                          \
        _Pragma("unroll") for (int ks = 0; ks < 4; ++ks)                      \
            oacc[dt] = mfma32(vf[dt * 4 + ks], pf[ks], oacc[dt]);             \
    __builtin_amdgcn_s_setprio(0);                                            \
  }

  STAGE(0, lds);

  for (int c = 0; c < 16; ++c) {
    char* cur = lds + (c & 1) * 32768;
    if (c + 1 < 16) {
      STAGE((c + 1) * 128, lds + ((c + 1) & 1) * 32768);
      asm volatile("s_waitcnt vmcnt(8)" ::: "memory");  // current tile landed
    } else {
      asm volatile("s_waitcnt vmcnt(0)" ::: "memory");
    }
    bar();

    SUBTILE(0, cur);
    SUBTILE(1, cur);

    bar();  // all waves done reading cur before restage
  }

  // epilogue: ctx[b][p][h*64 + d], d = (r&3)+8*(r>>2)+4*hi+32*dt
  lrun += __shfl_xor(lrun, 32);
  const float inv = 1.0f / lrun;
  const int b = bh >> 4, h = bh & 15;
  const int prow = q0 + w * 32 + l31;
  bf16* dst = ctx + ((size_t)(b * 512 + prow)) * 1024 + h * 64;
#pragma unroll
  for (int dt = 0; dt < 2; ++dt)
#pragma unroll
    for (int g4 = 0; g4 < 4; ++g4) {
      bf16x4 pk4;
#pragma unroll
      for (int r = 0; r < 4; ++r) pk4[r] = (bf16)(oacc[dt][g4 * 4 + r] * inv);
      *reinterpret_cast<bf16x4*>(dst + dt * 32 + g4 * 8 + hi * 4) = pk4;
    }
#undef STAGE
#undef SUBTILE
}

// ---------------- launch ----------------
extern "C" void kernel_launch(void* const* d_in, const int* in_sizes, int n_in,
                              void* d_out, int out_size, void* d_ws, size_t ws_size,
                              hipStream_t stream) {
  const float* ts = (const float*)d_in[0];
  const float* llm = (const float*)d_in[1];
  const float* qw = (const float*)d_in[2];
  const float* qb = (const float*)d_in[3];
  const float* kw = (const float*)d_in[4];
  const float* kb = (const float*)d_in[5];
  const float* vw = (const float*)d_in[6];
  const float* vb = (const float*)d_in[7];
  const float* ow = (const float*)d_in[8];
  const float* ob = (const float*)d_in[9];

  char* ws = (char*)d_ws;
  bf16* ts_bf = (bf16*)(ws + (0ull << 20));    // 8 MB
  bf16* llm_bf = (bf16*)(ws + (8ull << 20));   // 32 MB
  bf16* qw_bf = (bf16*)(ws + (40ull << 20));   // 2 MB
  bf16* kw_bf = (bf16*)(ws + (42ull << 20));   // 2 MB  } adjacent: [kw;vw]
  bf16* vw_bf = (bf16*)(ws + (44ull << 20));   // 2 MB  } = 2048x1024 concat
  bf16* ow_bf = (bf16*)(ws + (46ull << 20));   // 2 MB
  bf16* Qb = (bf16*)(ws + (48ull << 20));      // 8 MB  [B,H,P,64] (pre-scaled)
  bf16* Kb = (bf16*)(ws + (56ull << 20));      // 32 MB [B,H,S,64]
  bf16* VTb = (bf16*)(ws + (88ull << 20));     // 32 MB [B,H,64,S]
  bf16* ctx = (bf16*)(ws + (120ull << 20));    // 8 MB  [B,P,1024]

  cvt_all<<<2048, 256, 0, stream>>>(ts, llm, qw, kw, vw, ow,
                                    ts_bf, llm_bf, qw_bf, kw_bf, vw_bf, ow_bf);

  gemm_bt<MODE_Q><<<dim3(8, 32), 256, 0, stream>>>(ts_bf, qw_bf, qb, Qb);
  gemm256kv<<<512, 512, 0, stream>>>(llm_bf, kw_bf, kb, vb, Kb, VTb);
  attn_kernel<<<512, 256, 0, stream>>>(Qb, Kb, VTb, ctx);
  gemm_bt<MODE_F32><<<dim3(8, 32), 256, 0, stream>>>(ctx, ow_bf, ob, (void*)d_out);
}

// Round 15
// 188.591 us; speedup vs baseline: 1.0532x; 1.0319x over previous
//
#include <hip/hip_runtime.h>

// Cross-attention: B=8, P=512, S=2048, D_MODEL=1024, H=16, HD=64
#define DM 1024
#define B_ 8
#define P_ 512
#define S_ 2048

typedef __bf16 bf16;
typedef __bf16 bf16x4 __attribute__((ext_vector_type(4)));
typedef __bf16 bf16x8 __attribute__((ext_vector_type(8)));
typedef float f32x4 __attribute__((ext_vector_type(4)));
typedef float f32x16 __attribute__((ext_vector_type(16)));

__device__ __forceinline__ void gload_lds16(const void* g, void* l) {
  __builtin_amdgcn_global_load_lds(
      (const __attribute__((address_space(1))) unsigned int*)g,
      (__attribute__((address_space(3))) unsigned int*)l, 16, 0, 0);
}

__device__ __forceinline__ f32x4 mfma16(bf16x8 a, bf16x8 b, f32x4 c) {
  return __builtin_amdgcn_mfma_f32_16x16x32_bf16(a, b, c, 0, 0, 0);
}
__device__ __forceinline__ f32x16 mfma32(bf16x8 a, bf16x8 b, f32x16 c) {
  return __builtin_amdgcn_mfma_f32_32x32x16_bf16(a, b, c, 0, 0, 0);
}

__device__ __forceinline__ unsigned cvt_pk_bf16(float lo, float hi) {
  unsigned r;
  asm("v_cvt_pk_bf16_f32 %0, %1, %2" : "=v"(r) : "v"(lo), "v"(hi));
  return r;
}
// v_permlane32_swap_b32: new_a = {a.lo, b.lo}, new_b = {a.hi, b.hi}
__device__ __forceinline__ void plswap(unsigned& a, unsigned& b) {
  asm volatile("s_nop 1\n\tv_permlane32_swap_b32 %0, %1" : "+v"(a), "+v"(b));
}
__device__ __forceinline__ void bar() {
  asm volatile("" ::: "memory");
  __builtin_amdgcn_s_barrier();
  asm volatile("" ::: "memory");
}

union U8 { unsigned u[4]; bf16x8 v; };

// scale folded into Q projection: 1/sqrt(64) * log2(e)
#define QSCALE 0.18033688011112042f

// ---------------- fused f32 -> bf16 conversion (all 6 tensors, 1 launch) ----
__global__ void cvt_all(const float* __restrict__ ts, const float* __restrict__ llm,
                        const float* __restrict__ qw, const float* __restrict__ kw,
                        const float* __restrict__ vw, const float* __restrict__ ow,
                        bf16* __restrict__ ts_o, bf16* __restrict__ llm_o,
                        bf16* __restrict__ qw_o, bf16* __restrict__ kw_o,
                        bf16* __restrict__ vw_o, bf16* __restrict__ ow_o) {
  const int total = 24 << 18;
  int i = blockIdx.x * blockDim.x + threadIdx.x;
  const int stride = gridDim.x * blockDim.x;
  for (; i < total; i += stride) {
    int r = i >> 18;
    const float* in;
    bf16* out;
    int off;
    if (r < 4) { in = ts; out = ts_o; off = i; }
    else if (r < 20) { in = llm; out = llm_o; off = i - (4 << 18); }
    else if (r == 20) { in = qw; out = qw_o; off = i - (20 << 18); }
    else if (r == 21) { in = kw; out = kw_o; off = i - (21 << 18); }
    else if (r == 22) { in = vw; out = vw_o; off = i - (22 << 18); }
    else { in = ow; out = ow_o; off = i - (23 << 18); }
    float4 v = reinterpret_cast<const float4*>(in)[off];
    bf16x4 o;
    o[0] = (bf16)v.x; o[1] = (bf16)v.y; o[2] = (bf16)v.z; o[3] = (bf16)v.w;
    reinterpret_cast<bf16x4*>(out)[off] = o;
  }
}

enum { MODE_F32 = 0, MODE_Q = 1 };

// ---- 128x128 BT GEMM, 8 waves (2M x 4N, wave tile 64x32) for Q/O proj ------
// Same 2-barrier sync skeleton as the proven 4-wave version; only the wave ->
// subtile decomposition changed (1 -> 2 waves/SIMD for latency hiding).
template <int MODE>
__global__ __launch_bounds__(512) void gemm_bt(
    const bf16* __restrict__ A, const bf16* __restrict__ Bw,
    const float* __restrict__ bias, void* __restrict__ out) {
  __shared__ char As[16384];  // [128 rows][64 k * 2B]
  __shared__ char Bs[16384];
  const int tid = threadIdx.x;
  const int w = tid >> 6, lane = tid & 63;
  const int g = lane >> 4, l15 = lane & 15;
  const int tn = blockIdx.x, tm = blockIdx.y;
  const int wm = w >> 2, wn = w & 3;  // wave tile: M 64 rows x N 32 cols

  f32x4 acc[4][2] = {};

  const char* Abase = (const char*)A + (size_t)(tm * 128) * (DM * 2);
  const char* Bbase = (const char*)Bw + (size_t)(tn * 128) * (DM * 2);

  for (int kt = 0; kt < DM / 64; ++kt) {
#pragma unroll
    for (int i = 0; i < 2; ++i) {
      int f = i * 8192 + (w * 64 + lane) * 16;
      int row = f >> 7;          // 128B per row (64 bf16)
      int kb = f & 127;
      int src = kb ^ ((row & 7) << 4);
      gload_lds16(Abase + (size_t)row * (DM * 2) + kt * 128 + src,
                  As + i * 8192 + w * 1024);
      gload_lds16(Bbase + (size_t)row * (DM * 2) + kt * 128 + src,
                  Bs + i * 8192 + w * 1024);
    }
    __syncthreads();
#pragma unroll
    for (int kk = 0; kk < 2; ++kk) {
      bf16x8 af[4], bfr[2];
#pragma unroll
      for (int mi = 0; mi < 4; ++mi) {
        int row = wm * 64 + mi * 16 + l15;
        int off = row * 128 + ((kk * 64 + g * 16) ^ ((row & 7) << 4));
        af[mi] = *reinterpret_cast<const bf16x8*>(As + off);
      }
#pragma unroll
      for (int ni = 0; ni < 2; ++ni) {
        int row = wn * 32 + ni * 16 + l15;
        int off = row * 128 + ((kk * 64 + g * 16) ^ ((row & 7) << 4));
        bfr[ni] = *reinterpret_cast<const bf16x8*>(Bs + off);
      }
#pragma unroll
      for (int mi = 0; mi < 4; ++mi)
#pragma unroll
        for (int ni = 0; ni < 2; ++ni)
          acc[mi][ni] = mfma16(af[mi], bfr[ni], acc[mi][ni]);
    }
    __syncthreads();
  }

#pragma unroll
  for (int mi = 0; mi < 4; ++mi) {
#pragma unroll
    for (int ni = 0; ni < 2; ++ni) {
      const int n = tn * 128 + wn * 32 + ni * 16 + l15;
      const float bn = bias[n];
      const int mb = tm * 128 + wm * 64 + mi * 16 + g * 4;
#pragma unroll
      for (int r = 0; r < 4; ++r) {
        const int m = mb + r;
        const float v = acc[mi][ni][r] + bn;
        if constexpr (MODE == MODE_F32) {
          ((float*)out)[(size_t)m * 1024 + n] = v;
        } else {  // MODE_Q: fold softmax scale*log2e into Q
          const int b = m >> 9, p = m & 511, h = n >> 6, d = n & 63;
          ((bf16*)out)[((size_t)((b * 16 + h) * 512 + p)) * 64 + d] = (bf16)(v * QSCALE);
        }
      }
    }
  }
}

// ------- 256x256 4-phase pipelined BT GEMM, K+V projections fused (N=2048) ---
__global__ __launch_bounds__(512, 2) void gemm256kv(
    const bf16* __restrict__ A, const bf16* __restrict__ Bw,
    const float* __restrict__ kb, const float* __restrict__ vb,
    bf16* __restrict__ Kout, bf16* __restrict__ VTout) {
  __shared__ char lds[131072];  // A: [0,64K), B: [64K,128K)
  const int tid = threadIdx.x;
  const int w = tid >> 6, lane = tid & 63;
  const int g = lane >> 4, l15 = lane & 15;
  const int wm = w >> 2, wn = w & 3;

  const int id = blockIdx.x;
  const int nid = (id & 7) * 64 + (id >> 3);
  const int tn = nid & 7, tm = nid >> 3;

  const int f0 = tid * 16, f1 = f0 + 8192;
  const int r0 = f0 >> 7, r1 = f1 >> 7;
  const size_t so0 = (size_t)r0 * 2048 + ((f0 & 127) ^ ((r0 & 7) << 4));
  const size_t so1 = (size_t)r1 * 2048 + ((f1 & 127) ^ ((r1 & 7) << 4));

  const char* Ab = (const char*)A + (size_t)(tm * 256) * 2048;
  const char* Bb = (const char*)Bw + (size_t)(tn * 256) * 2048;

#define STG(OP, HALF, KT)                                                      \
  {                                                                            \
    const char* base = ((OP) ? Bb : Ab) + (size_t)((HALF) * 128) * 2048 +      \
                       (size_t)(KT) * 128;                                     \
    char* dst = lds + (OP) * 65536 + ((((KT) & 1) * 2 + (HALF)) * 16384);      \
    gload_lds16(base + so0, dst + f0);                                         \
    gload_lds16(base + so1, dst + f1);                                         \
  }

  f32x4 acc[8][4] = {};
  bf16x8 a[4][2], b0[2][2], b1[2][2];

#define RD_A(MH)                                                               \
  _Pragma("unroll") for (int mi = 0; mi < 4; ++mi) _Pragma("unroll")           \
      for (int kk = 0; kk < 2; ++kk) {                                         \
    int lr = (MH) * 64 + mi * 16 + l15;                                        \
    int off = (((unsigned)(kt & 1) * 2 + wm) * 16384) + lr * 128 +             \
              ((kk * 64 + g * 16) ^ ((lr & 7) << 4));                          \
    a[mi][kk] = *reinterpret_cast<const bf16x8*>(lds + off);                   \
  }
#define RD_B(NH, DST)                                                          \
  _Pragma("unroll") for (int ni = 0; ni < 2; ++ni) _Pragma("unroll")           \
      for (int kk = 0; kk < 2; ++kk) {                                         \
    int lr = (wn & 1) * 64 + ((NH) * 2 + ni) * 16 + l15;                       \
    int off = 65536 + (((unsigned)(kt & 1) * 2 + (wn >> 1)) * 16384) +         \
              lr * 128 + ((kk * 64 + g * 16) ^ ((lr & 7) << 4));               \
    DST[ni][kk] = *reinterpret_cast<const bf16x8*>(lds + off);                 \
  }
#define MM(MH, NH, B)                                                          \
  __builtin_amdgcn_s_setprio(1);                                              \
  _Pragma("unroll") for (int mi = 0; mi < 4; ++mi) _Pragma("unroll")           \
      for (int ni = 0; ni < 2; ++ni) _Pragma("unroll")                         \
      for (int kk = 0; kk < 2; ++kk)                                           \
          acc[(MH)*4 + mi][(NH)*2 + ni] =                                      \
              mfma16(a[mi][kk], B[ni][kk], acc[(MH)*4 + mi][(NH)*2 + ni]);     \
  __builtin_amdgcn_s_setprio(0);

  STG(0, 0, 0); STG(1, 0, 0); STG(0, 1, 0); STG(1, 1, 0);
  STG(1, 1, 1); STG(0, 0, 1); STG(1, 0, 1);
  asm volatile("s_waitcnt vmcnt(6)" ::: "memory");
  bar();

  for (int kt = 0; kt < 16; ++kt) {
    RD_A(0); RD_B(0, b0);
    if (kt + 1 < 16) STG(0, 1, kt + 1);
    bar();
    MM(0, 0, b0);
    bar();
    RD_B(1, b1);
    bar();
    MM(0, 1, b1);
    bar();
    RD_A(1);
    if (kt + 2 < 16) STG(1, 1, kt + 2);
    bar();
    MM(1, 0, b0);
    bar();
    if (kt + 2 < 16) { STG(0, 0, kt + 2); STG(1, 0, kt + 2); }
    if (kt < 14) {
      asm volatile("s_waitcnt vmcnt(6)" ::: "memory");
    } else {
      asm volatile("s_waitcnt vmcnt(0)" ::: "memory");
    }
    bar();
    MM(1, 1, b1);
    bar();
  }

#pragma unroll
  for (int am = 0; am < 8; ++am) {
#pragma unroll
    for (int an = 0; an < 4; ++an) {
      const int n = tn * 256 + wn * 64 + an * 16 + l15;
      const int mb = tm * 256 + wm * 128 + am * 16 + g * 4;
      const int b = mb >> 11, s = mb & 2047;
      if (n >= 1024) {  // VT output: [B][H][64][S], rows r = consecutive s
        const int h = (n - 1024) >> 6, d = (n - 1024) & 63;
        const float bn = vb[n - 1024];
        bf16x4 pk;
#pragma unroll
        for (int r = 0; r < 4; ++r) pk[r] = (bf16)(acc[am][an][r] + bn);
        *reinterpret_cast<bf16x4*>(VTout + ((size_t)((b * 16 + h) * 64 + d)) * 2048 + s) = pk;
      } else {  // K output: [B][H][S][64]
        const int h = n >> 6, d = n & 63;
        const float bn = kb[n];
#pragma unroll
        for (int r = 0; r < 4; ++r)
          Kout[((size_t)((b * 16 + h) * 2048 + s + r)) * 64 + d] =
              (bf16)(acc[am][an][r] + bn);
      }
    }
  }
#undef STG
#undef RD_A
#undef RD_B
#undef MM
}

// ---------------- Flash attention: chunk=128, proven sync skeleton ----------
// STAGE(c+1) -> counted vmcnt -> bar -> compute (two 64-kv sub-tiles) -> bar.
// LDS: 2 x (16KB K[128][128B] + 16KB V[64][256B]) = 64KB; 2 blocks/CU.
__global__ __launch_bounds__(256) void attn_kernel(
    const bf16* __restrict__ Q, const bf16* __restrict__ K,
    const bf16* __restrict__ VT, bf16* __restrict__ ctx) {
  __shared__ char lds[65536];
  const int tid = threadIdx.x;
  const int w = tid >> 6, lane = tid & 63;
  const int l31 = lane & 31, hi = lane >> 5;

  const int n = blockIdx.x;
  const int xcd = n & 7, mm = n >> 3;
  const int bh = xcd + ((mm >> 2) << 3);
  const int qt = mm & 3;
  const int q0 = qt * 128;

  const char* Kb = (const char*)(K + (size_t)bh * 2048 * 64);
  const char* Vb = (const char*)(VT + (size_t)bh * 64 * 2048);

  const char* Qrow = (const char*)(Q + ((size_t)bh * 512 + q0 + w * 32 + l31) * 64);
  bf16x8 qf[4];
#pragma unroll
  for (int kk = 0; kk < 4; ++kk)
    qf[kk] = *reinterpret_cast<const bf16x8*>(Qrow + kk * 32 + hi * 16);

  float lrun = 0.f;
  f32x16 oacc[2] = {};

#define STAGE(S0, BUF)                                                        \
  {                                                                           \
    _Pragma("unroll") for (int i = 0; i < 4; ++i) {                           \
      int f = i * 4096 + (w * 64 + lane) * 16;                                \
      int krow = f >> 7, kbyte = f & 127;                                     \
      gload_lds16(Kb + (size_t)((S0) + krow) * 128 +                          \
                      (kbyte ^ ((krow & 7) << 4)),                            \
                  (BUF) + i * 4096 + w * 1024);                               \
      int vrow = f >> 8, vbyte = f & 255;                                     \
      gload_lds16(Vb + (size_t)vrow * 4096 + (size_t)(S0) * 2 +               \
                      (vbyte ^ ((vrow & 7) << 4)),                            \
                  (BUF) + 16384 + i * 4096 + w * 1024);                       \
    }                                                                         \
  }

#define SUBTILE(T2, CUR)                                                      \
  {                                                                           \
    f32x16 sa[2] = {};                                                        \
    __builtin_amdgcn_s_setprio(1);                                            \
    _Pragma("unroll") for (int t = 0; t < 2; ++t) {                           \
      _Pragma("unroll") for (int kk = 0; kk < 4; ++kk) {                      \
        int row = (T2) * 64 + t * 32 + l31;                                   \
        int off = row * 128 + ((kk * 32 + hi * 16) ^ ((row & 7) << 4));       \
        bf16x8 kf = *reinterpret_cast<const bf16x8*>((CUR) + off);            \
        sa[t] = mfma32(kf, qf[kk], sa[t]);                                    \
      }                                                                       \
    }                                                                         \
    __builtin_amdgcn_s_setprio(0);                                            \
    bf16x8 vf[8];                                                             \
    _Pragma("unroll") for (int dt = 0; dt < 2; ++dt)                          \
        _Pragma("unroll") for (int ks = 0; ks < 4; ++ks) {                    \
      int row = dt * 32 + l31;                                                \
      int col = (T2) * 128 + ks * 32 + hi * 16;                               \
      int off = 16384 + row * 256 + (col ^ ((row & 7) << 4));                 \
      vf[dt * 4 + ks] = *reinterpret_cast<const bf16x8*>((CUR) + off);        \
    }                                                                         \
    bf16x8 pf[4];                                                             \
    _Pragma("unroll") for (int t = 0; t < 2; ++t)                             \
        _Pragma("unroll") for (int h2 = 0; h2 < 2; ++h2) {                    \
      float p[8];                                                             \
      _Pragma("unroll") for (int j = 0; j < 8; ++j) {                         \
        p[j] = __builtin_amdgcn_exp2f(sa[t][8 * h2 + j]);                     \
        lrun += p[j];                                                         \
      }                                                                       \
      unsigned a0 = cvt_pk_bf16(p[0], p[1]);                                  \
      unsigned a1 = cvt_pk_bf16(p[2], p[3]);                                  \
      unsigned a2 = cvt_pk_bf16(p[4], p[5]);                                  \
      unsigned a3 = cvt_pk_bf16(p[6], p[7]);                                  \
      plswap(a0, a2);                                                         \
      plswap(a1, a3);                                                         \
      U8 u;                                                                   \
      u.u[0] = a0; u.u[1] = a1; u.u[2] = a2; u.u[3] = a3;                     \
      pf[t * 2 + h2] = u.v;                                                   \
    }                                                                         \
    __builtin_amdgcn_s_setprio(1);                                            \
    _Pragma("unroll") for (int dt = 0; dt < 2; ++dt)                          \
        _Pragma("unroll") for (int ks = 0; ks < 4; ++ks)                      \
            oacc[dt] = mfma32(vf[dt * 4 + ks], pf[ks], oacc[dt]);             \
    __builtin_amdgcn_s_setprio(0);                                            \
  }

  STAGE(0, lds);

  for (int c = 0; c < 16; ++c) {
    char* cur = lds + (c & 1) * 32768;
    if (c + 1 < 16) {
      STAGE((c + 1) * 128, lds + ((c + 1) & 1) * 32768);
      asm volatile("s_waitcnt vmcnt(8)" ::: "memory");  // current tile landed
    } else {
      asm volatile("s_waitcnt vmcnt(0)" ::: "memory");
    }
    bar();

    SUBTILE(0, cur);
    SUBTILE(1, cur);

    bar();  // all waves done reading cur before restage
  }

  // epilogue: ctx[b][p][h*64 + d], d = (r&3)+8*(r>>2)+4*hi+32*dt
  lrun += __shfl_xor(lrun, 32);
  const float inv = 1.0f / lrun;
  const int b = bh >> 4, h = bh & 15;
  const int prow = q0 + w * 32 + l31;
  bf16* dst = ctx + ((size_t)(b * 512 + prow)) * 1024 + h * 64;
#pragma unroll
  for (int dt = 0; dt < 2; ++dt)
#pragma unroll
    for (int g4 = 0; g4 < 4; ++g4) {
      bf16x4 pk4;
#pragma unroll
      for (int r = 0; r < 4; ++r) pk4[r] = (bf16)(oacc[dt][g4 * 4 + r] * inv);
      *reinterpret_cast<bf16x4*>(dst + dt * 32 + g4 * 8 + hi * 4) = pk4;
    }
#undef STAGE
#undef SUBTILE
}

// ---------------- launch ----------------
extern "C" void kernel_launch(void* const* d_in, const int* in_sizes, int n_in,
                              void* d_out, int out_size, void* d_ws, size_t ws_size,
                              hipStream_t stream) {
  const float* ts = (const float*)d_in[0];
  const float* llm = (const float*)d_in[1];
  const float* qw = (const float*)d_in[2];
  const float* qb = (const float*)d_in[3];
  const float* kw = (const float*)d_in[4];
  const float* kb = (const float*)d_in[5];
  const float* vw = (const float*)d_in[6];
  const float* vb = (const float*)d_in[7];
  const float* ow = (const float*)d_in[8];
  const float* ob = (const float*)d_in[9];

  char* ws = (char*)d_ws;
  bf16* ts_bf = (bf16*)(ws + (0ull << 20));    // 8 MB
  bf16* llm_bf = (bf16*)(ws + (8ull << 20));   // 32 MB
  bf16* qw_bf = (bf16*)(ws + (40ull << 20));   // 2 MB
  bf16* kw_bf = (bf16*)(ws + (42ull << 20));   // 2 MB  } adjacent: [kw;vw]
  bf16* vw_bf = (bf16*)(ws + (44ull << 20));   // 2 MB  } = 2048x1024 concat
  bf16* ow_bf = (bf16*)(ws + (46ull << 20));   // 2 MB
  bf16* Qb = (bf16*)(ws + (48ull << 20));      // 8 MB  [B,H,P,64] (pre-scaled)
  bf16* Kb = (bf16*)(ws + (56ull << 20));      // 32 MB [B,H,S,64]
  bf16* VTb = (bf16*)(ws + (88ull << 20));     // 32 MB [B,H,64,S]
  bf16* ctx = (bf16*)(ws + (120ull << 20));    // 8 MB  [B,P,1024]

  cvt_all<<<2048, 256, 0, stream>>>(ts, llm, qw, kw, vw, ow,
                                    ts_bf, llm_bf, qw_bf, kw_bf, vw_bf, ow_bf);

  gemm_bt<MODE_Q><<<dim3(8, 32), 512, 0, stream>>>(ts_bf, qw_bf, qb, Qb);
  gemm256kv<<<512, 512, 0, stream>>>(llm_bf, kw_bf, kb, vb, Kb, VTb);
  attn_kernel<<<512, 256, 0, stream>>>(Qb, Kb, VTb, ctx);
  gemm_bt<MODE_F32><<<dim3(8, 32), 512, 0, stream>>>(ctx, ow_bf, ob, (void*)d_out);
}